// Round 8
// baseline (274.043 us; speedup 1.0000x reference)
//
#include <hip/hip_runtime.h>
#include <math.h>

#define REG_COEF 25.0f
#define B 8
#define H 3
#define N 4096

typedef _Float16 f16x8 __attribute__((ext_vector_type(8)));
typedef float f32x16 __attribute__((ext_vector_type(16)));

static constexpr int NX = B * N;          // 32768 sample points (A-role)
static constexpr int NY = B * H * N;      // 98304 reflected points (B-role)
static constexpr int NM = 2 * B * H * N;  // 196608 per-point mins

// ws layout (float units):
//   [0, 262144)        : Afrag — NX points x 16 f16 slots (32 B each)
//   [262144, 1048576)  : Bfrag — NY points x 16 f16 slots (32 B each)
//   [1048576, 1245184) : mins (196608 floats)

__global__ void prep_kernel(const float* __restrict__ pts, const float* __restrict__ ypred,
                            char* __restrict__ Af, char* __restrict__ Bf,
                            float* __restrict__ mins, float* __restrict__ out)
{
    int idx = blockIdx.x * blockDim.x + threadIdx.x;
    if (idx == 0) {
        float reg = 0.f;
        for (int b = 0; b < B; ++b) {
            float n[H][3];
            #pragma unroll
            for (int h = 0; h < H; ++h) {
                float a0 = ypred[b * 12 + h * 4 + 0];
                float a1 = ypred[b * 12 + h * 4 + 1];
                float a2 = ypred[b * 12 + h * 4 + 2];
                float inv = rsqrtf(a0 * a0 + a1 * a1 + a2 * a2);
                n[h][0] = a0 * inv; n[h][1] = a1 * inv; n[h][2] = a2 * inv;
            }
            float s = 0.f;
            #pragma unroll
            for (int c = 0; c < H; ++c)
                #pragma unroll
                for (int e = 0; e < H; ++e) {
                    float g = n[c][0] * n[e][0] + n[c][1] * n[e][1] + n[c][2] * n[e][2];
                    if (c == e) g -= 1.f;
                    s += g * g;
                }
            reg += sqrtf(s);
        }
        out[0] = REG_COEF * reg;   // reduce_kernel accumulates on top
    }

    union { _Float16 h[16]; uint4 u[2]; } pk;

    if (idx < NX) {
        // X point -> A slots: a = -2*coord, hi/lo split; w = |q|^2 hi/lo
        const float* p = pts + (size_t)idx * 3;
        float x = p[0], y = p[1], z = p[2];
        float w = x * x + y * y + z * z;
        float ax = -2.f * x, ay = -2.f * y, az = -2.f * z;
        _Float16 ahx = (_Float16)ax, ahy = (_Float16)ay, ahz = (_Float16)az;
        _Float16 wh = (_Float16)w;
        pk.h[0] = ahx; pk.h[1] = ahy; pk.h[2] = ahz;
        pk.h[3] = (_Float16)(ax - (float)ahx);
        pk.h[4] = (_Float16)(ay - (float)ahy);
        pk.h[5] = (_Float16)(az - (float)ahz);
        pk.h[6] = ahx; pk.h[7] = ahy; pk.h[8] = ahz;
        pk.h[9] = wh; pk.h[10] = (_Float16)(w - (float)wh);
        pk.h[11] = (_Float16)1.f; pk.h[12] = (_Float16)1.f;
        pk.h[13] = (_Float16)0.f; pk.h[14] = (_Float16)0.f; pk.h[15] = (_Float16)0.f;
        uint4* dst = (uint4*)(Af + (size_t)idx * 32);
        dst[0] = pk.u[0]; dst[1] = pk.u[1];
    } else if (idx < NX + NY) {
        int t = idx - NX;            // (b*H + h)*N + nn
        int nn = t & (N - 1);
        int bh = t >> 12;
        int b = bh / H, h = bh - b * H;
        float a0 = ypred[b * 12 + h * 4 + 0];
        float a1 = ypred[b * 12 + h * 4 + 1];
        float a2 = ypred[b * 12 + h * 4 + 2];
        float off = ypred[b * 12 + h * 4 + 3];
        float inv = rsqrtf(a0 * a0 + a1 * a1 + a2 * a2);
        a0 *= inv; a1 *= inv; a2 *= inv;
        const float* p = pts + ((size_t)b * N + nn) * 3;
        float x0 = p[0], x1 = p[1], x2 = p[2];
        float dist = a0 * x0 + a1 * x1 + a2 * x2 + off;
        float x = fmaf(-2.f * dist, a0, x0);
        float y = fmaf(-2.f * dist, a1, x1);
        float z = fmaf(-2.f * dist, a2, x2);
        float w = x * x + y * y + z * z;
        _Float16 thx = (_Float16)x, thy = (_Float16)y, thz = (_Float16)z;
        _Float16 wh = (_Float16)w;
        pk.h[0] = thx; pk.h[1] = thy; pk.h[2] = thz;
        pk.h[3] = thx; pk.h[4] = thy; pk.h[5] = thz;
        pk.h[6] = (_Float16)(x - (float)thx);
        pk.h[7] = (_Float16)(y - (float)thy);
        pk.h[8] = (_Float16)(z - (float)thz);
        pk.h[9] = (_Float16)1.f; pk.h[10] = (_Float16)1.f;
        pk.h[11] = wh; pk.h[12] = (_Float16)(w - (float)wh);
        pk.h[13] = (_Float16)0.f; pk.h[14] = (_Float16)0.f; pk.h[15] = (_Float16)0.f;
        uint4* dst = (uint4*)(Bf + (size_t)t * 32);
        dst[0] = pk.u[0]; dst[1] = pk.u[1];
    } else if (idx < NX + NY + NM) {
        mins[idx - NX - NY] = __uint_as_float(0x7F800000u);  // +inf
    }
}

// 1536 blocks: [tsplit(8)][qsplit(8)][h(3)][b(8)]
// Block: 4 waves x 128 queries (4 A-frags in regs), streams 512 targets
// (16 B-tiles). Each mfma_f32_32x32x16_f16 yields a 32x32 tile of FULL
// distances d(q,t). One pass serves both chamfer directions: per-row reg
// chains (q-side) + per-col lane tree -> LDS atomicMin (t-side).
__global__ __launch_bounds__(256, 6) void chamfer_kernel(const char* __restrict__ Af,
                                                         const char* __restrict__ Bf,
                                                         float* __restrict__ mins)
{
    __shared__ unsigned tmin[512];
    int bid = blockIdx.x;
    int ts = bid & 7;
    int qs = (bid >> 3) & 7;
    int rest = bid >> 6;        // 0..23
    int hh = rest % 3;
    int b  = rest / 3;

    int tid = threadIdx.x;
    int w = tid >> 6;
    int lane = tid & 63;
    int l31 = lane & 31, kb = lane >> 5;

    for (int j = tid; j < 512; j += 256) tmin[j] = 0x7F800000u;
    __syncthreads();

    int qbase = qs * 512 + w * 128;   // query offset within batch b
    f16x8 A[4];
    #pragma unroll
    for (int a = 0; a < 4; ++a)
        A[a] = *(const f16x8*)(Af + ((size_t)(b * N + qbase + a * 32 + l31)) * 32 + kb * 16);

    f32x16 mq[4];
    #pragma unroll
    for (int a = 0; a < 4; ++a)
        #pragma unroll
        for (int r = 0; r < 16; ++r) mq[a][r] = INFINITY;

    const char* Bbase = Bf + ((size_t)((b * H + hh) * N + ts * 512 + l31)) * 32 + kb * 16;
    f16x8 Bcur = *(const f16x8*)(Bbase);
    f32x16 zero = {};

    for (int bt = 0; bt < 16; ++bt) {
        f16x8 Bnext = Bcur;
        if (bt < 15) Bnext = *(const f16x8*)(Bbase + (size_t)(bt + 1) * 1024);
        float tacc = INFINITY;
        #pragma unroll
        for (int a = 0; a < 4; ++a) {
            f32x16 D = __builtin_amdgcn_mfma_f32_32x32x16_f16(A[a], Bcur, zero, 0, 0, 0);
            #pragma unroll
            for (int r = 0; r < 16; ++r) mq[a][r] = fminf(mq[a][r], D[r]);
            float t0 = fminf(fminf(D[0], D[1]), fminf(D[2], D[3]));
            float t1 = fminf(fminf(D[4], D[5]), fminf(D[6], D[7]));
            float t2 = fminf(fminf(D[8], D[9]), fminf(D[10], D[11]));
            float t3 = fminf(fminf(D[12], D[13]), fminf(D[14], D[15]));
            tacc = fminf(tacc, fminf(fminf(t0, t1), fminf(t2, t3)));
        }
        // both kb-halves hit the same slot; LDS atomic merges them (2 lanes/slot is free)
        atomicMin(&tmin[bt * 32 + l31], __float_as_uint(fmaxf(tacc, 0.f)));
        Bcur = Bnext;
    }

    // q-side: reduce each row-chain across the 32 columns (lanes)
    #pragma unroll
    for (int a = 0; a < 4; ++a) {
        #pragma unroll
        for (int r = 0; r < 16; ++r) {
            float v = mq[a][r];
            v = fminf(v, __shfl_xor(v, 1, 64));
            v = fminf(v, __shfl_xor(v, 2, 64));
            v = fminf(v, __shfl_xor(v, 4, 64));
            v = fminf(v, __shfl_xor(v, 8, 64));
            v = fminf(v, __shfl_xor(v, 16, 64));
            if (l31 == 0) {
                int row = (r & 3) + 8 * (r >> 2) + 4 * kb;
                atomicMin((unsigned*)&mins[(size_t)(b * H + hh) * N + qbase + a * 32 + row],
                          __float_as_uint(fmaxf(v, 0.f)));
            }
        }
    }

    __syncthreads();
    float* minsT = mins + (size_t)B * H * N + (size_t)(b * H + hh) * N + ts * 512;
    for (int j = tid; j < 512; j += 256)
        atomicMin((unsigned*)&minsT[j], tmin[j]);
}

__global__ void reduce_kernel(const float* __restrict__ mins, float* __restrict__ out)
{
    int tid = blockIdx.x * blockDim.x + threadIdx.x;  // 192*256 = 49152 threads
    float s = 0.f;
    #pragma unroll
    for (int k = 0; k < 4; ++k) s += mins[tid + k * 49152];
    #pragma unroll
    for (int off = 32; off > 0; off >>= 1) s += __shfl_down(s, off);
    if ((threadIdx.x & 63) == 0) atomicAdd(out, s);
}

extern "C" void kernel_launch(void* const* d_in, const int* in_sizes, int n_in,
                              void* d_out, int out_size, void* d_ws, size_t ws_size,
                              hipStream_t stream)
{
    const float* pts = (const float*)d_in[0];   // (8,4096,3) fp32
    const float* yp  = (const float*)d_in[1];   // (8,3,4) fp32
    float* out = (float*)d_out;
    float* ws  = (float*)d_ws;

    char* Af   = (char*)ws;                     // 1 MB
    char* Bf   = (char*)(ws + 262144);          // 3 MB
    float* mins = ws + 1048576;                 // 196608 floats

    prep_kernel<<<1280, 256, 0, stream>>>(pts, yp, Af, Bf, mins, out);
    chamfer_kernel<<<1536, 256, 0, stream>>>(Af, Bf, mins);
    reduce_kernel<<<192, 256, 0, stream>>>(mins, out);
}

// Round 9
// 65.093 us; speedup vs baseline: 4.2100x; 4.2100x over previous
//
#include <hip/hip_runtime.h>
#include <math.h>

#define REG_COEF 25.0f
#define B 8
#define H 3
#define N 4096

typedef _Float16 f16x8 __attribute__((ext_vector_type(8)));
typedef float f32x16 __attribute__((ext_vector_type(16)));

static constexpr int NX = B * N;          // 32768 sample points
static constexpr int NY = B * H * N;      // 98304 reflected points
static constexpr int NM = 2 * B * H * N;  // 196608 per-point mins

// Four packed fragment arrays (32 B per point, 16 f16 slots):
//  A-pack (query role):  [ahx,ahy,ahz, alx,aly,alz, ahx,ahy,ahz, wh,wl, 1,1, 0,0,0]  a=-2p
//  B-pack (target role): [thx,thy,thz, thx,thy,thz, tlx,tly,tlz, 1,1, twh,twl, 0,0,0]
// dot(A,B) = (ah+al)·th + ah·tl + |q|^2 + |t|^2 ~= |q-t|^2  (~1e-4 abs err)
// ws layout (float units):
//   [0,       262144)  : ApkX   (1 MB)
//   [262144,  524288)  : BpkX   (1 MB)
//   [524288, 1310720)  : ApkY   (3 MB)
//   [1310720,2097152)  : BpkY   (3 MB)
//   [2097152,2293760)  : mins   (196608 floats)

__global__ void prep_kernel(const float* __restrict__ pts, const float* __restrict__ ypred,
                            char* __restrict__ ApkX, char* __restrict__ BpkX,
                            char* __restrict__ ApkY, char* __restrict__ BpkY,
                            float* __restrict__ mins, float* __restrict__ out)
{
    int idx = blockIdx.x * blockDim.x + threadIdx.x;
    if (idx == 0) {
        float reg = 0.f;
        for (int b = 0; b < B; ++b) {
            float n[H][3];
            #pragma unroll
            for (int h = 0; h < H; ++h) {
                float a0 = ypred[b * 12 + h * 4 + 0];
                float a1 = ypred[b * 12 + h * 4 + 1];
                float a2 = ypred[b * 12 + h * 4 + 2];
                float inv = rsqrtf(a0 * a0 + a1 * a1 + a2 * a2);
                n[h][0] = a0 * inv; n[h][1] = a1 * inv; n[h][2] = a2 * inv;
            }
            float s = 0.f;
            #pragma unroll
            for (int c = 0; c < H; ++c)
                #pragma unroll
                for (int e = 0; e < H; ++e) {
                    float g = n[c][0] * n[e][0] + n[c][1] * n[e][1] + n[c][2] * n[e][2];
                    if (c == e) g -= 1.f;
                    s += g * g;
                }
            reg += sqrtf(s);
        }
        out[0] = REG_COEF * reg;   // reduce_kernel accumulates on top
    }

    union { _Float16 h[16]; uint4 u[2]; } pa, pb;

    if (idx < NX) {
        const float* p = pts + (size_t)idx * 3;
        float x = p[0], y = p[1], z = p[2];
        float w = x * x + y * y + z * z;
        // A-pack of X
        float ax = -2.f * x, ay = -2.f * y, az = -2.f * z;
        _Float16 ahx = (_Float16)ax, ahy = (_Float16)ay, ahz = (_Float16)az;
        _Float16 wh = (_Float16)w;
        pa.h[0] = ahx; pa.h[1] = ahy; pa.h[2] = ahz;
        pa.h[3] = (_Float16)(ax - (float)ahx);
        pa.h[4] = (_Float16)(ay - (float)ahy);
        pa.h[5] = (_Float16)(az - (float)ahz);
        pa.h[6] = ahx; pa.h[7] = ahy; pa.h[8] = ahz;
        pa.h[9] = wh; pa.h[10] = (_Float16)(w - (float)wh);
        pa.h[11] = (_Float16)1.f; pa.h[12] = (_Float16)1.f;
        pa.h[13] = (_Float16)0.f; pa.h[14] = (_Float16)0.f; pa.h[15] = (_Float16)0.f;
        ((uint4*)(ApkX + (size_t)idx * 32))[0] = pa.u[0];
        ((uint4*)(ApkX + (size_t)idx * 32))[1] = pa.u[1];
        // B-pack of X
        _Float16 thx = (_Float16)x, thy = (_Float16)y, thz = (_Float16)z;
        pb.h[0] = thx; pb.h[1] = thy; pb.h[2] = thz;
        pb.h[3] = thx; pb.h[4] = thy; pb.h[5] = thz;
        pb.h[6] = (_Float16)(x - (float)thx);
        pb.h[7] = (_Float16)(y - (float)thy);
        pb.h[8] = (_Float16)(z - (float)thz);
        pb.h[9] = (_Float16)1.f; pb.h[10] = (_Float16)1.f;
        pb.h[11] = wh; pb.h[12] = (_Float16)(w - (float)wh);
        pb.h[13] = (_Float16)0.f; pb.h[14] = (_Float16)0.f; pb.h[15] = (_Float16)0.f;
        ((uint4*)(BpkX + (size_t)idx * 32))[0] = pb.u[0];
        ((uint4*)(BpkX + (size_t)idx * 32))[1] = pb.u[1];
    } else if (idx < NX + NY) {
        int t = idx - NX;            // (b*H + h)*N + nn
        int nn = t & (N - 1);
        int bh = t >> 12;
        int b = bh / H, h = bh - b * H;
        float a0 = ypred[b * 12 + h * 4 + 0];
        float a1 = ypred[b * 12 + h * 4 + 1];
        float a2 = ypred[b * 12 + h * 4 + 2];
        float off = ypred[b * 12 + h * 4 + 3];
        float inv = rsqrtf(a0 * a0 + a1 * a1 + a2 * a2);
        a0 *= inv; a1 *= inv; a2 *= inv;
        const float* p = pts + ((size_t)b * N + nn) * 3;
        float x0 = p[0], x1 = p[1], x2 = p[2];
        float dist = a0 * x0 + a1 * x1 + a2 * x2 + off;
        float x = fmaf(-2.f * dist, a0, x0);
        float y = fmaf(-2.f * dist, a1, x1);
        float z = fmaf(-2.f * dist, a2, x2);
        float w = x * x + y * y + z * z;
        // B-pack of Y
        _Float16 thx = (_Float16)x, thy = (_Float16)y, thz = (_Float16)z;
        _Float16 wh = (_Float16)w;
        pb.h[0] = thx; pb.h[1] = thy; pb.h[2] = thz;
        pb.h[3] = thx; pb.h[4] = thy; pb.h[5] = thz;
        pb.h[6] = (_Float16)(x - (float)thx);
        pb.h[7] = (_Float16)(y - (float)thy);
        pb.h[8] = (_Float16)(z - (float)thz);
        pb.h[9] = (_Float16)1.f; pb.h[10] = (_Float16)1.f;
        pb.h[11] = wh; pb.h[12] = (_Float16)(w - (float)wh);
        pb.h[13] = (_Float16)0.f; pb.h[14] = (_Float16)0.f; pb.h[15] = (_Float16)0.f;
        ((uint4*)(BpkY + (size_t)t * 32))[0] = pb.u[0];
        ((uint4*)(BpkY + (size_t)t * 32))[1] = pb.u[1];
        // A-pack of Y
        float ax = -2.f * x, ay = -2.f * y, az = -2.f * z;
        _Float16 ahx = (_Float16)ax, ahy = (_Float16)ay, ahz = (_Float16)az;
        pa.h[0] = ahx; pa.h[1] = ahy; pa.h[2] = ahz;
        pa.h[3] = (_Float16)(ax - (float)ahx);
        pa.h[4] = (_Float16)(ay - (float)ahy);
        pa.h[5] = (_Float16)(az - (float)ahz);
        pa.h[6] = ahx; pa.h[7] = ahy; pa.h[8] = ahz;
        pa.h[9] = wh; pa.h[10] = (_Float16)(w - (float)wh);
        pa.h[11] = (_Float16)1.f; pa.h[12] = (_Float16)1.f;
        pa.h[13] = (_Float16)0.f; pa.h[14] = (_Float16)0.f; pa.h[15] = (_Float16)0.f;
        ((uint4*)(ApkY + (size_t)t * 32))[0] = pa.u[0];
        ((uint4*)(ApkY + (size_t)t * 32))[1] = pa.u[1];
    } else if (idx < NX + NY + NM) {
        mins[idx - NX - NY] = __uint_as_float(0x7F800000u);  // +inf
    }
}

// 1536 blocks: [ts(2)][qs(16)][h(3)][b(8)][dir(2)]
// Block: 4 waves x 64 queries (2 A-frags in regs), streams 2048 targets
// (64 B-tiles, processed in pairs). Per pair: 4 MFMA + 32 v_min3 folds.
// One direction per block (q-side min only) — no LDS, no inner atomics.
__global__ __launch_bounds__(256, 4) void chamfer_kernel(const char* __restrict__ ApkX,
                                                         const char* __restrict__ BpkX,
                                                         const char* __restrict__ ApkY,
                                                         const char* __restrict__ BpkY,
                                                         float* __restrict__ mins)
{
    int bid = blockIdx.x;
    int ts = bid & 1;
    int qs = (bid >> 1) & 15;
    int rest = bid >> 5;        // 0..47
    int hh = rest % 3;
    int tmp = rest / 3;         // 0..15
    int b = tmp & 7;
    int dir = tmp >> 3;

    int tid = threadIdx.x;
    int w = tid >> 6;
    int lane = tid & 63;
    int l31 = lane & 31, kb = lane >> 5;

    const char* Aq;
    const char* Bt;
    float* mq_base;
    if (dir == 0) {
        Aq = ApkX + (size_t)b * N * 32;
        Bt = BpkY + (size_t)(b * H + hh) * N * 32;
        mq_base = mins + (size_t)(b * H + hh) * N;
    } else {
        Aq = ApkY + (size_t)(b * H + hh) * N * 32;
        Bt = BpkX + (size_t)b * N * 32;
        mq_base = mins + (size_t)B * H * N + (size_t)(b * H + hh) * N;
    }
    int qbase = qs * 256 + w * 64;
    Aq += (size_t)qbase * 32;
    Bt += (size_t)ts * 2048 * 32;

    f16x8 A0 = *(const f16x8*)(Aq + ((size_t)(l31)) * 32 + kb * 16);
    f16x8 A1 = *(const f16x8*)(Aq + ((size_t)(32 + l31)) * 32 + kb * 16);

    f32x16 mq0, mq1;
    #pragma unroll
    for (int r = 0; r < 16; ++r) { mq0[r] = INFINITY; mq1[r] = INFINITY; }

    const char* Bp = Bt + (size_t)l31 * 32 + kb * 16;
    f16x8 B0 = *(const f16x8*)(Bp);
    f16x8 B1 = *(const f16x8*)(Bp + 1024);
    f32x16 zero = {};

    for (int bt = 0; bt < 64; bt += 2) {
        // prefetch next pair (may read past slice into adjacent ws region; unused)
        f16x8 Bn0 = *(const f16x8*)(Bp + (size_t)(bt + 2) * 1024);
        f16x8 Bn1 = *(const f16x8*)(Bp + (size_t)(bt + 3) * 1024);
        f32x16 D0 = __builtin_amdgcn_mfma_f32_32x32x16_f16(A0, B0, zero, 0, 0, 0);
        f32x16 D1 = __builtin_amdgcn_mfma_f32_32x32x16_f16(A0, B1, zero, 0, 0, 0);
        #pragma unroll
        for (int r = 0; r < 16; ++r)
            mq0[r] = fminf(mq0[r], fminf(D0[r], D1[r]));   // v_min3_f32
        f32x16 D2 = __builtin_amdgcn_mfma_f32_32x32x16_f16(A1, B0, zero, 0, 0, 0);
        f32x16 D3 = __builtin_amdgcn_mfma_f32_32x32x16_f16(A1, B1, zero, 0, 0, 0);
        #pragma unroll
        for (int r = 0; r < 16; ++r)
            mq1[r] = fminf(mq1[r], fminf(D2[r], D3[r]));   // v_min3_f32
        B0 = Bn0; B1 = Bn1;
    }

    // reduce each query row across the 32 columns (lanes), then global atomicMin
    #pragma unroll
    for (int a = 0; a < 2; ++a) {
        #pragma unroll
        for (int r = 0; r < 16; ++r) {
            float v = (a == 0) ? mq0[r] : mq1[r];
            v = fminf(v, __shfl_xor(v, 1, 64));
            v = fminf(v, __shfl_xor(v, 2, 64));
            v = fminf(v, __shfl_xor(v, 4, 64));
            v = fminf(v, __shfl_xor(v, 8, 64));
            v = fminf(v, __shfl_xor(v, 16, 64));
            if (l31 == 0) {
                int row = (r & 3) + 8 * (r >> 2) + 4 * kb;
                atomicMin((unsigned*)&mq_base[qbase + a * 32 + row],
                          __float_as_uint(fmaxf(v, 0.f)));
            }
        }
    }
}

__global__ void reduce_kernel(const float* __restrict__ mins, float* __restrict__ out)
{
    int tid = blockIdx.x * blockDim.x + threadIdx.x;  // 192*256 = 49152 threads
    float s = 0.f;
    #pragma unroll
    for (int k = 0; k < 4; ++k) s += mins[tid + k * 49152];
    #pragma unroll
    for (int off = 32; off > 0; off >>= 1) s += __shfl_down(s, off);
    if ((threadIdx.x & 63) == 0) atomicAdd(out, s);
}

extern "C" void kernel_launch(void* const* d_in, const int* in_sizes, int n_in,
                              void* d_out, int out_size, void* d_ws, size_t ws_size,
                              hipStream_t stream)
{
    const float* pts = (const float*)d_in[0];   // (8,4096,3) fp32
    const float* yp  = (const float*)d_in[1];   // (8,3,4) fp32
    float* out = (float*)d_out;
    float* ws  = (float*)d_ws;

    char* ApkX = (char*)ws;                     // 1 MB
    char* BpkX = (char*)(ws + 262144);          // 1 MB
    char* ApkY = (char*)(ws + 524288);          // 3 MB
    char* BpkY = (char*)(ws + 1310720);         // 3 MB
    float* mins = ws + 2097152;                 // 196608 floats

    prep_kernel<<<1280, 256, 0, stream>>>(pts, yp, ApkX, BpkX, ApkY, BpkY, mins, out);
    chamfer_kernel<<<1536, 256, 0, stream>>>(ApkX, BpkX, ApkY, BpkY, mins);
    reduce_kernel<<<192, 256, 0, stream>>>(mins, out);
}